// Round 14
// baseline (238.760 us; speedup 1.0000x reference)
//
#include <hip/hip_runtime.h>
#include <math.h>

#define Hd 264
#define Wd 480
#define HW (Hd * Wd)
#define NB 16
#define NC 9
#define KK 50
#define NPLANE 144
#define NDET 800
#define NK 450
#define K1CH 8
#define F4PC (HW / 4 / K1CH)       // 3960
#define SLAB_CAP 512
#define SCAP 1024
#define FB_CAP 16384
#define TB_F 0.998f
#define PI_F 3.14159274101257324f
#define TWO_PI_F 6.28318548202514648f

__device__ const float DIMM[9][3] = {
    {3.99331126f, 1.54370861f, 1.64175497f},
    {0.295f, 1.6f, 0.3175f},
    {1.34645161f, 1.55322581f, 0.3883871f},
    {2.503f, 1.72f, 1.077f},
    {9.1775f, 2.95f, 2.3425f},
    {10.3655102f, 3.31632653f, 2.45469388f},
    {6.016911083f, 3.412001685f, 2.2783185f},
    {4.824963f, 2.046904f, 1.78939f},
    {8.8040879f, 2.916193f, 2.07649252f}};

__device__ const float ACENT[4] = {0.0f, 1.57079637050628662f, 3.14159274101257324f, -1.57079637050628662f};

__device__ __forceinline__ unsigned long long mkkey(float v, unsigned int idx) {
    return ((unsigned long long)__float_as_uint(v) << 32) | (unsigned long long)(0xFFFFFFFFu - idx);
}

// Kernel 1 (R10-proven): streaming threshold filter. Appends >=TB pixels to a
// per-(plane,chunk) slab + raw count. Zeroes the fan-in counters for K2
// (kernel-boundary visibility). Graph-replay safe.
__global__ __launch_bounds__(256) void thresh_scan(const float* __restrict__ cls,
                                                   unsigned long long* __restrict__ slabs,
                                                   int* __restrict__ slabCnt,
                                                   int* __restrict__ batchCnt,
                                                   int* __restrict__ validCnt) {
    __shared__ unsigned long long sbuf[SLAB_CAP];
    __shared__ int scnt;

    const int plane = blockIdx.y;
    const int chunk = blockIdx.x;
    const int tid = threadIdx.x;
    if (tid == 0) scnt = 0;
    if (plane == 0 && chunk == 0) {
        if (tid < NB) batchCnt[tid] = 0;
        if (tid == NB) validCnt[0] = 0;
    }
    __syncthreads();

    const float4* hp4 = (const float4*)(cls + (size_t)plane * HW) + (size_t)chunk * F4PC;
    const unsigned int base = (unsigned int)(chunk * F4PC * 4);

    for (int q = tid; q < F4PC; q += 256) {
        const float4 v = hp4[q];
        const unsigned int i0 = base + 4u * (unsigned int)q;
        if (v.x >= TB_F) { const int p = atomicAdd(&scnt, 1); if (p < SLAB_CAP) sbuf[p] = mkkey(v.x, i0); }
        if (v.y >= TB_F) { const int p = atomicAdd(&scnt, 1); if (p < SLAB_CAP) sbuf[p] = mkkey(v.y, i0 + 1); }
        if (v.z >= TB_F) { const int p = atomicAdd(&scnt, 1); if (p < SLAB_CAP) sbuf[p] = mkkey(v.z, i0 + 2); }
        if (v.w >= TB_F) { const int p = atomicAdd(&scnt, 1); if (p < SLAB_CAP) sbuf[p] = mkkey(v.w, i0 + 3); }
    }
    __syncthreads();
    const int n = min(scnt, SLAB_CAP);
    unsigned long long* dst = slabs + (size_t)(plane * K1CH + chunk) * SLAB_CAP;
    for (int j = tid; j < n; j += 256) dst[j] = sbuf[j];
    if (tid == 0) slabCnt[plane * K1CH + chunk] = scnt;  // raw (overflow-detectable)
}

struct ShSel {
    unsigned long long S[SCAP];
    int soff[K1CH + 1];
    int s_scnt, s_over;
    unsigned long long wmax[4];
    unsigned long long sprev;
};
struct ShBat {
    unsigned long long S[NK];
    unsigned int sidx[NK];
    float bSc[KK]; int bInd[KK]; int bCls[KK];
    float sdet[KK][26];
};
struct ShVal { int ind[NDET]; float sc[NDET]; int cl[NDET]; };
union ShAll { ShSel sel; ShBat bat; ShVal val; };

// Kernel 2: one block per plane. Phase A: NMS-verify + exact rank (R10 logic).
// Fan-in 1 (last of 9 plane blocks per batch): rank 450 keys, det math for the
// batch's 50 dets, write out rows 0-13 + cls, publish det arrays. Fan-in 2
// (last of 16 batch blocks): batch-global segment-max valid row for all 800.
// No spinning anywhere; all published buffers deterministic -> replay-safe.
__global__ __launch_bounds__(256) void select_all(const float* __restrict__ cls,
                                                  const float* __restrict__ regs,
                                                  const float* __restrict__ calib,
                                                  float* __restrict__ out,
                                                  const unsigned long long* __restrict__ slabs,
                                                  const int* __restrict__ slabCnt,
                                                  unsigned long long* __restrict__ planeKeys,
                                                  int* __restrict__ batchCnt,
                                                  int* __restrict__ validCnt,
                                                  float* __restrict__ dScore,
                                                  int* __restrict__ dInd,
                                                  int* __restrict__ dCls,
                                                  unsigned long long* __restrict__ fbBuf,
                                                  int* __restrict__ fbCnt) {
    __shared__ ShAll u;
    __shared__ int s_last, s_vlast;

    const int p = blockIdx.x;
    const int tid = threadIdx.x;
    const int lane = tid & 63, wid = tid >> 6;
    const float* hp = cls + (size_t)p * HW;

    // ---------- Phase A: per-plane NMS-verify + exact top-50 ----------
    if (tid == 0) { u.sel.s_scnt = 0; u.sel.s_over = 0; }
    __syncthreads();
    if (tid < K1CH) {
        const int c = slabCnt[p * K1CH + tid];
        u.sel.soff[tid + 1] = min(c, SLAB_CAP);
        if (c > SLAB_CAP) atomicAdd(&u.sel.s_over, 1);
    }
    __syncthreads();
    if (tid == 0) {
        u.sel.soff[0] = 0;
        for (int c = 1; c <= K1CH; ++c) u.sel.soff[c] += u.sel.soff[c - 1];
    }
    __syncthreads();
    const int n = u.sel.soff[K1CH];

    if (!u.sel.s_over) {
        for (int j = tid; j < n; j += 256) {
            int lo = 0, hi = K1CH;
            while (hi - lo > 1) { const int mid = (lo + hi) >> 1; if (u.sel.soff[mid] <= j) lo = mid; else hi = mid; }
            const unsigned long long k = slabs[(size_t)(p * K1CH + lo) * SLAB_CAP + (j - u.sel.soff[lo])];
            const unsigned int idx = 0xFFFFFFFFu - (unsigned int)(k & 0xFFFFFFFFull);
            const float v = __uint_as_float((unsigned int)(k >> 32));
            const int y = (int)idx / Wd, x = (int)idx - ((int)idx / Wd) * Wd;
            const int ylo = max(y - 2, 0), yhi = min(y + 2, Hd - 1);
            const int xlo = max(x - 2, 0), xhi = min(x + 2, Wd - 1);
            float wm = -INFINITY;
            for (int yy = ylo; yy <= yhi; ++yy)
                for (int xx = xlo; xx <= xhi; ++xx)
                    wm = fmaxf(wm, hp[yy * Wd + xx]);
            if (v == wm) {
                const int q = atomicAdd(&u.sel.s_scnt, 1);
                if (q < SCAP) u.sel.S[q] = k;
            }
        }
    }
    __syncthreads();
    const int sc = u.sel.s_scnt;

    if (!u.sel.s_over && sc >= KK && sc <= SCAP) {
        // Prefix-closed survivor set -> in-set rank == global rank. Exact.
        for (int idx = tid; idx < sc; idx += 256) {
            const unsigned long long k = u.sel.S[idx];
            int r = 0;
            for (int j = 0; j < sc; ++j) r += (u.sel.S[j] > k) ? 1 : 0;
            if (r < KK) planeKeys[p * KK + r] = k;
        }
    } else {
        // Fallback (any-data correct): brute-force plane NMS + keyed argmax.
        if (tid == 0) fbCnt[p] = 0;
        for (int j = tid; j < KK; j += 256) planeKeys[p * KK + j] = 0;
        __syncthreads();
        unsigned long long* fb = fbBuf + (size_t)p * FB_CAP;
        for (int px = tid; px < HW; px += 256) {
            const float v = hp[px];
            const int y = px / Wd, x = px - (px / Wd) * Wd;
            const int ylo = max(y - 2, 0), yhi = min(y + 2, Hd - 1);
            const int xlo = max(x - 2, 0), xhi = min(x + 2, Wd - 1);
            float wm = -INFINITY;
            for (int yy = ylo; yy <= yhi; ++yy)
                for (int xx = xlo; xx <= xhi; ++xx)
                    wm = fmaxf(wm, hp[yy * Wd + xx]);
            if (v == wm) {
                const int q = atomicAdd(&fbCnt[p], 1);
                if (q < FB_CAP) fb[q] = mkkey(v, (unsigned int)px);
            }
        }
        __syncthreads();
        const int nn = min(fbCnt[p], FB_CAP);
        unsigned long long prevk = ~0ull;
        for (int it = 0; it < KK; ++it) {
            unsigned long long mk = 0;
            for (int j = tid; j < nn; j += 256) {
                unsigned long long k = fb[j];
                if (k == prevk) { fb[j] = 0; k = 0; }
                if (k > mk) mk = k;
            }
            for (int s = 32; s > 0; s >>= 1) {
                const unsigned long long o = __shfl_down(mk, s);
                if (o > mk) mk = o;
            }
            if (lane == 0) u.sel.wmax[wid] = mk;
            __syncthreads();
            if (tid == 0) {
                unsigned long long m = u.sel.wmax[0];
                if (u.sel.wmax[1] > m) m = u.sel.wmax[1];
                if (u.sel.wmax[2] > m) m = u.sel.wmax[2];
                if (u.sel.wmax[3] > m) m = u.sel.wmax[3];
                planeKeys[p * KK + it] = m;
                u.sel.sprev = m;
            }
            __syncthreads();
            prevk = u.sel.sprev;
        }
    }

    // ---------- Fan-in 1: last of the batch's 9 plane blocks continues ----------
    __threadfence();
    __syncthreads();
    if (tid == 0) s_last = (atomicAdd(&batchCnt[p / NC], 1) == NC - 1) ? 1 : 0;
    __syncthreads();
    if (!s_last) return;
    __threadfence();  // acquire other planes' planeKeys

    const int b = p / NC;
    for (int j = tid; j < NK; j += 256) {
        const unsigned long long pk = planeKeys[b * NK + j];
        u.bat.sidx[j] = 0xFFFFFFFFu - (unsigned int)(pk & 0xFFFFFFFFull);
        u.bat.S[j] = (pk & 0xFFFFFFFF00000000ull) | (unsigned long long)(0xFFFFFFFFu - (unsigned int)j);
    }
    __syncthreads();
    for (int idx = tid; idx < NK; idx += 256) {
        const unsigned long long k = u.bat.S[idx];
        int r = 0;
        for (int j = 0; j < NK; ++j) r += (u.bat.S[j] > k) ? 1 : 0;
        if (r < KK) {
            const float scv = __uint_as_float((unsigned int)(k >> 32));
            const int iv = (int)u.bat.sidx[idx];
            const int cv = idx / KK;
            u.bat.bSc[r] = scv; u.bat.bInd[r] = iv; u.bat.bCls[r] = cv;
            dScore[b * KK + r] = scv; dInd[b * KK + r] = iv; dCls[b * KK + r] = cv;
        }
    }
    __syncthreads();

    // Det math for this batch's 50 dets: 1300 scattered loads, LDS-staged.
    for (int pr = tid; pr < KK * 26; pr += 256) {
        const int d = pr / 26, c = pr - (pr / 26) * 26;
        const int ch = (c < 6) ? c : c + 16;  // 0-5, 22-24, 25-40, 41
        const int i0 = u.bat.bInd[d];
        const int ind = (i0 >= 0 && i0 < HW) ? i0 : 0;
        u.bat.sdet[d][c] = regs[(size_t)b * 46 * HW + (size_t)ch * HW + (size_t)ind];
    }
    __syncthreads();

    if (tid < KK) {
        const int i = b * KK + tid;
        const float* s = u.bat.sdet[tid];
        const int cls_ = u.bat.bCls[tid];
        const float score = u.bat.bSc[tid];
        const int i0 = u.bat.bInd[tid];
        const int ind = (i0 >= 0 && i0 < HW) ? i0 : 0;

        const float x = (float)(ind % Wd);
        const float y = (float)(ind / Wd);
        const float r0 = fmaxf(s[0], 0.0f), r1 = fmaxf(s[1], 0.0f);
        const float r2 = fmaxf(s[2], 0.0f), r3 = fmaxf(s[3], 0.0f);
        const float cx = x + s[4];
        const float cy = y + s[5];

        const float bx1 = fminf(fmaxf((cx - r0) * 4.0f, 0.0f), 1920.0f);
        const float by1 = fminf(fmaxf((cy - r1) * 4.0f, 0.0f), 1056.0f);
        const float bx2 = fminf(fmaxf((cx + r2) * 4.0f, 0.0f), 1920.0f);
        const float by2 = fminf(fmaxf((cy + r3) * 4.0f, 0.0f), 1056.0f);

        const float dim0 = expf(s[6]) * DIMM[cls_][0];
        const float dim1 = expf(s[7]) * DIMM[cls_][1];
        const float dim2 = expf(s[8]) * DIMM[cls_][2];

        const float sig = 1.0f / (1.0f + expf(-s[25]));
        const float depth = fminf(fmaxf(1.0f / sig - 1.0f, 0.1f), 200.0f);

        const float fu = calib[0], cu = calib[2], fv = calib[5], cv = calib[6];
        const float bxo = calib[3] / -fu;
        const float byo = calib[7] / -fv;
        const float locx = (cx * 4.0f - cu) * depth / fu + bxo;
        const float locy = (cy * 4.0f - cv) * depth / fv + byo;

        float best = -INFINITY;
        int bidx = 0;
#pragma unroll
        for (int t = 0; t < 4; ++t) {
            const float l0 = s[9 + 2 * t], l1 = s[9 + 2 * t + 1];
            const float mm = fmaxf(l0, l1);
            const float p1 = expf(l1 - mm) / (expf(l0 - mm) + expf(l1 - mm));
            if (p1 > best) { best = p1; bidx = t; }
        }
        const float sel0 = s[17 + 2 * bidx], sel1 = s[17 + 2 * bidx + 1];
        float alpha = atanf(sel0 / sel1) + ACENT[bidx];
        const float ray = atanf(locx / depth);
        float roty = alpha + ray;
        if (roty > PI_F) roty -= TWO_PI_F;
        if (roty < -PI_F) roty += TWO_PI_F;
        if (alpha > PI_F) alpha -= TWO_PI_F;
        if (alpha < -PI_F) alpha += TWO_PI_F;

        float* o = out + (size_t)i * 14;
        o[0] = bx1; o[1] = by1; o[2] = bx2; o[3] = by2;
        o[4] = dim0; o[5] = dim1; o[6] = dim2;
        o[7] = depth;
        o[8] = locx; o[9] = locy; o[10] = depth;
        o[11] = roty; o[12] = alpha;
        o[13] = score;
        out[NDET * 15 + i] = (float)cls_;
    }

    // ---------- Fan-in 2: last of the 16 batch blocks computes valid row ----------
    __threadfence();
    __syncthreads();
    if (tid == 0) s_vlast = (atomicAdd(&validCnt[0], 1) == NB - 1) ? 1 : 0;
    __syncthreads();
    if (!s_vlast) return;
    __threadfence();  // acquire all batches' det arrays

    for (int j = tid; j < NDET; j += 256) {
        u.val.ind[j] = dInd[j];
        u.val.sc[j] = dScore[j];
        u.val.cl[j] = dCls[j];
    }
    __syncthreads();
    for (int i = tid; i < NDET; i += 256) {
        const bool th = u.val.sc[i] >= 0.29f;
        const float key_i = th ? (float)u.val.cl[i] * 10000.0f - (float)i : -INFINITY;
        float m = -INFINITY;
        for (int j = 0; j < NDET; ++j) {
            if (u.val.ind[j] == u.val.ind[i] && u.val.sc[j] >= 0.29f) {
                m = fmaxf(m, (float)u.val.cl[j] * 10000.0f - (float)j);
            }
        }
        out[NDET * 14 + i] = (th && key_i == m) ? 1.0f : 0.0f;
    }
}

extern "C" void kernel_launch(void* const* d_in, const int* in_sizes, int n_in,
                              void* d_out, int out_size, void* d_ws, size_t ws_size,
                              hipStream_t stream) {
    const float* cls = (const float*)d_in[0];
    const float* regs = (const float*)d_in[1];
    const float* calib = (const float*)d_in[2];
    float* out = (float*)d_out;
    char* ws = (char*)d_ws;

    // ws layout (all regions rewritten each launch before being read)
    int* slabCnt = (int*)ws;                                          // 1152*4 B
    int* batchCnt = (int*)(ws + 8192);                                // 16*4
    int* validCnt = (int*)(ws + 8192 + 64);                           // 4
    int* fbCnt = (int*)(ws + 8192 + 128);                             // 144*4
    unsigned long long* planeKeys = (unsigned long long*)(ws + 16384); // 57,600 B
    float* dScore = (float*)(ws + 73984);                             // 3200
    int* dInd = (int*)(ws + 77184);                                   // 3200
    int* dCls = (int*)(ws + 80384);                                   // 3200
    unsigned long long* slabs = (unsigned long long*)(ws + 98304);    // 1152*512*8 = 4,718,592
    unsigned long long* fbBuf = (unsigned long long*)(ws + 98304 + 4718592);  // 144*16384*8

    hipLaunchKernelGGL(thresh_scan, dim3(K1CH, NPLANE), dim3(256), 0, stream,
                       cls, slabs, slabCnt, batchCnt, validCnt);
    hipLaunchKernelGGL(select_all, dim3(NPLANE), dim3(256), 0, stream,
                       cls, regs, calib, out, slabs, slabCnt, planeKeys,
                       batchCnt, validCnt, dScore, dInd, dCls, fbBuf, fbCnt);
}

// Round 15
// 59.281 us; speedup vs baseline: 4.0276x; 4.0276x over previous
//
#include <hip/hip_runtime.h>
#include <math.h>

#define Hd 264
#define Wd 480
#define HW (Hd * Wd)
#define NB 16
#define NC 9
#define KK 50
#define NPLANE 144
#define NDET 800
#define NK 450
#define K1CH 8
#define F4PC (HW / 4 / K1CH)       // 3960
#define SLAB_CAP 512
#define SCAP 1024
#define FB_CAP 16384
#define TB_F 0.998f
#define PI_F 3.14159274101257324f
#define TWO_PI_F 6.28318548202514648f

__device__ const float DIMM[9][3] = {
    {3.99331126f, 1.54370861f, 1.64175497f},
    {0.295f, 1.6f, 0.3175f},
    {1.34645161f, 1.55322581f, 0.3883871f},
    {2.503f, 1.72f, 1.077f},
    {9.1775f, 2.95f, 2.3425f},
    {10.3655102f, 3.31632653f, 2.45469388f},
    {6.016911083f, 3.412001685f, 2.2783185f},
    {4.824963f, 2.046904f, 1.78939f},
    {8.8040879f, 2.916193f, 2.07649252f}};

__device__ const float ACENT[4] = {0.0f, 1.57079637050628662f, 3.14159274101257324f, -1.57079637050628662f};

__device__ __forceinline__ unsigned long long mkkey(float v, unsigned int idx) {
    return ((unsigned long long)__float_as_uint(v) << 32) | (unsigned long long)(0xFFFFFFFFu - idx);
}

// Kernel 1: streaming threshold filter (proven <=10us incl. gap, R14 timing).
// Pixels >= TB_F appended to per-(plane,chunk) slab + raw count. Replay-safe:
// everything rewritten each launch; no cross-block protocols anywhere.
__global__ __launch_bounds__(256) void thresh_scan(const float* __restrict__ cls,
                                                   unsigned long long* __restrict__ slabs,
                                                   int* __restrict__ slabCnt) {
    __shared__ unsigned long long sbuf[SLAB_CAP];
    __shared__ int scnt;

    const int plane = blockIdx.y;
    const int chunk = blockIdx.x;
    const int tid = threadIdx.x;
    if (tid == 0) scnt = 0;
    __syncthreads();

    const float4* hp4 = (const float4*)(cls + (size_t)plane * HW) + (size_t)chunk * F4PC;
    const unsigned int base = (unsigned int)(chunk * F4PC * 4);

    for (int q = tid; q < F4PC; q += 256) {
        const float4 v = hp4[q];
        const unsigned int i0 = base + 4u * (unsigned int)q;
        if (v.x >= TB_F) { const int p = atomicAdd(&scnt, 1); if (p < SLAB_CAP) sbuf[p] = mkkey(v.x, i0); }
        if (v.y >= TB_F) { const int p = atomicAdd(&scnt, 1); if (p < SLAB_CAP) sbuf[p] = mkkey(v.y, i0 + 1); }
        if (v.z >= TB_F) { const int p = atomicAdd(&scnt, 1); if (p < SLAB_CAP) sbuf[p] = mkkey(v.z, i0 + 2); }
        if (v.w >= TB_F) { const int p = atomicAdd(&scnt, 1); if (p < SLAB_CAP) sbuf[p] = mkkey(v.w, i0 + 3); }
    }
    __syncthreads();
    const int n = min(scnt, SLAB_CAP);
    unsigned long long* dst = slabs + (size_t)(plane * K1CH + chunk) * SLAB_CAP;
    for (int j = tid; j < n; j += 256) dst[j] = sbuf[j];
    if (tid == 0) slabCnt[plane * K1CH + chunk] = scnt;  // raw (overflow-detectable)
}

// Kernel 2: one block per plane — NMS-verify candidates (direct 25-point window
// reads) + exact rank into planeKeys. NO fan-in, no cross-block reads of
// freshly-written data (avoids the cross-XCD dirty-line penalty, R12-R14).
// Fallback (overflow / <50 survivors): brute-force full-plane NMS + keyed
// argmax via global scratch. Bit-exact keys; prefix-closed -> exact ranks.
__global__ __launch_bounds__(256) void select_topk(const float* __restrict__ cls,
                                                   const unsigned long long* __restrict__ slabs,
                                                   const int* __restrict__ slabCnt,
                                                   unsigned long long* __restrict__ planeKeys,
                                                   unsigned long long* __restrict__ fbBuf,
                                                   int* __restrict__ fbCnt) {
    __shared__ unsigned long long S[SCAP];
    __shared__ int soff[K1CH + 1];
    __shared__ int s_scnt, s_over;
    __shared__ unsigned long long wmax[4];
    __shared__ unsigned long long sprev;

    const int p = blockIdx.x;
    const int tid = threadIdx.x;
    const int lane = tid & 63, wid = tid >> 6;
    const float* hp = cls + (size_t)p * HW;

    if (tid == 0) { s_scnt = 0; s_over = 0; }
    __syncthreads();
    if (tid < K1CH) {
        const int c = slabCnt[p * K1CH + tid];
        soff[tid + 1] = min(c, SLAB_CAP);
        if (c > SLAB_CAP) atomicAdd(&s_over, 1);
    }
    __syncthreads();
    if (tid == 0) {
        soff[0] = 0;
        for (int c = 1; c <= K1CH; ++c) soff[c] += soff[c - 1];
    }
    __syncthreads();
    const int n = soff[K1CH];

    if (!s_over) {
        for (int j = tid; j < n; j += 256) {
            int lo = 0, hi = K1CH;
            while (hi - lo > 1) { const int mid = (lo + hi) >> 1; if (soff[mid] <= j) lo = mid; else hi = mid; }
            const unsigned long long k = slabs[(size_t)(p * K1CH + lo) * SLAB_CAP + (j - soff[lo])];
            const unsigned int idx = 0xFFFFFFFFu - (unsigned int)(k & 0xFFFFFFFFull);
            const float v = __uint_as_float((unsigned int)(k >> 32));
            const int y = (int)idx / Wd, x = (int)idx - ((int)idx / Wd) * Wd;
            const int ylo = max(y - 2, 0), yhi = min(y + 2, Hd - 1);
            const int xlo = max(x - 2, 0), xhi = min(x + 2, Wd - 1);
            float wm = -INFINITY;
            for (int yy = ylo; yy <= yhi; ++yy)
                for (int xx = xlo; xx <= xhi; ++xx)
                    wm = fmaxf(wm, hp[yy * Wd + xx]);
            if (v == wm) {
                const int q = atomicAdd(&s_scnt, 1);
                if (q < SCAP) S[q] = k;
            }
        }
    }
    __syncthreads();
    const int sc = s_scnt;

    if (!s_over && sc >= KK && sc <= SCAP) {
        // Prefix-closed survivor set -> in-set rank == global rank. Exact.
        for (int idx = tid; idx < sc; idx += 256) {
            const unsigned long long k = S[idx];
            int r = 0;
            for (int j = 0; j < sc; ++j) r += (S[j] > k) ? 1 : 0;
            if (r < KK) planeKeys[p * KK + r] = k;
        }
        return;
    }

    // Fallback (any-data correct): brute-force full-plane NMS + keyed argmax.
    if (tid == 0) fbCnt[p] = 0;
    for (int j = tid; j < KK; j += 256) planeKeys[p * KK + j] = 0;
    __syncthreads();
    unsigned long long* fb = fbBuf + (size_t)p * FB_CAP;
    for (int px = tid; px < HW; px += 256) {
        const float v = hp[px];
        const int y = px / Wd, x = px - (px / Wd) * Wd;
        const int ylo = max(y - 2, 0), yhi = min(y + 2, Hd - 1);
        const int xlo = max(x - 2, 0), xhi = min(x + 2, Wd - 1);
        float wm = -INFINITY;
        for (int yy = ylo; yy <= yhi; ++yy)
            for (int xx = xlo; xx <= xhi; ++xx)
                wm = fmaxf(wm, hp[yy * Wd + xx]);
        if (v == wm) {
            const int q = atomicAdd(&fbCnt[p], 1);
            if (q < FB_CAP) fb[q] = mkkey(v, (unsigned int)px);
        }
    }
    __syncthreads();
    const int nn = min(fbCnt[p], FB_CAP);
    unsigned long long prevk = ~0ull;
    for (int it = 0; it < KK; ++it) {
        unsigned long long mk = 0;
        for (int j = tid; j < nn; j += 256) {
            unsigned long long k = fb[j];
            if (k == prevk) { fb[j] = 0; k = 0; }
            if (k > mk) mk = k;
        }
        for (int s = 32; s > 0; s >>= 1) {
            const unsigned long long o = __shfl_down(mk, s);
            if (o > mk) mk = o;
        }
        if (lane == 0) wmax[wid] = mk;
        __syncthreads();
        if (tid == 0) {
            unsigned long long m = wmax[0];
            if (wmax[1] > m) m = wmax[1];
            if (wmax[2] > m) m = wmax[2];
            if (wmax[3] > m) m = wmax[3];
            planeKeys[p * KK + it] = m;
            sprev = m;
        }
        __syncthreads();
        prevk = sprev;
    }
}

// Kernel 3 (R8-proven): per batch — exact top-50 of 450 unique keys by ranking.
__global__ __launch_bounds__(256) void batch_topk(const unsigned long long* __restrict__ planeKeys,
                                                  float* __restrict__ dScore, int* __restrict__ dInd,
                                                  int* __restrict__ dCls) {
    __shared__ unsigned long long k2[NK];
    __shared__ unsigned int sidx[NK];

    const int b = blockIdx.x;
    const int tid = threadIdx.x;
    for (int j = tid; j < NK; j += 256) {
        const unsigned long long pk = planeKeys[b * NK + j];
        sidx[j] = 0xFFFFFFFFu - (unsigned int)(pk & 0xFFFFFFFFull);
        k2[j] = (pk & 0xFFFFFFFF00000000ull) | (unsigned long long)(0xFFFFFFFFu - (unsigned int)j);
    }
    __syncthreads();

    for (int idx = tid; idx < NK; idx += 256) {
        const unsigned long long k = k2[idx];
        int r = 0;
        for (int j = 0; j < NK; ++j) r += (k2[j] > k) ? 1 : 0;
        if (r < KK) {
            dScore[b * KK + r] = __uint_as_float((unsigned int)(k >> 32));
            dInd[b * KK + r] = (int)sidx[idx];
            dCls[b * KK + r] = idx / KK;
        }
    }
}

// Kernel 4 (R8/R10-proven): fused per-detection finalize, 800 blocks x 64.
__global__ __launch_bounds__(64) void finalize(const float* __restrict__ regs,
                                               const float* __restrict__ calib,
                                               const float* __restrict__ dScore,
                                               const int* __restrict__ dInd,
                                               const int* __restrict__ dCls,
                                               float* __restrict__ out) {
    __shared__ float s[26];
    const int i = blockIdx.x;
    const int lane = threadIdx.x;
    const int ind0 = dInd[i];
    const int ind = (ind0 >= 0 && ind0 < HW) ? ind0 : 0;
    const int b = i / KK;

    if (lane < 26) {
        const int ch = (lane < 6) ? lane : lane + 16;  // 0-5, 22-24, 25-40, 41
        s[lane] = regs[(size_t)b * 46 * HW + (size_t)ch * HW + (size_t)ind];
    }

    float m = -INFINITY;
    for (int j = lane; j < NDET; j += 64) {
        if (dInd[j] == ind0 && dScore[j] >= 0.29f) {
            m = fmaxf(m, (float)dCls[j] * 10000.0f - (float)j);
        }
    }
#pragma unroll
    for (int sft = 32; sft > 0; sft >>= 1) m = fmaxf(m, __shfl_down(m, sft));
    __syncthreads();
    if (lane != 0) return;

    const int cls = dCls[i];
    const float score = dScore[i];
    const bool th = score >= 0.29f;
    const float key_i = th ? (float)cls * 10000.0f - (float)i : -INFINITY;
    const bool valid = th && (key_i == m);

    const float x = (float)(ind % Wd);
    const float y = (float)(ind / Wd);

    const float r0 = fmaxf(s[0], 0.0f), r1 = fmaxf(s[1], 0.0f);
    const float r2 = fmaxf(s[2], 0.0f), r3 = fmaxf(s[3], 0.0f);
    const float cx = x + s[4];
    const float cy = y + s[5];

    const float bx1 = fminf(fmaxf((cx - r0) * 4.0f, 0.0f), 1920.0f);
    const float by1 = fminf(fmaxf((cy - r1) * 4.0f, 0.0f), 1056.0f);
    const float bx2 = fminf(fmaxf((cx + r2) * 4.0f, 0.0f), 1920.0f);
    const float by2 = fminf(fmaxf((cy + r3) * 4.0f, 0.0f), 1056.0f);

    const float dim0 = expf(s[6]) * DIMM[cls][0];
    const float dim1 = expf(s[7]) * DIMM[cls][1];
    const float dim2 = expf(s[8]) * DIMM[cls][2];

    const float sig = 1.0f / (1.0f + expf(-s[25]));
    const float depth = fminf(fmaxf(1.0f / sig - 1.0f, 0.1f), 200.0f);

    const float fu = calib[0], cu = calib[2], fv = calib[5], cv = calib[6];
    const float bxo = calib[3] / -fu;
    const float byo = calib[7] / -fv;
    const float locx = (cx * 4.0f - cu) * depth / fu + bxo;
    const float locy = (cy * 4.0f - cv) * depth / fv + byo;

    float best = -INFINITY;
    int bidx = 0;
#pragma unroll
    for (int t = 0; t < 4; ++t) {
        const float l0 = s[9 + 2 * t], l1 = s[9 + 2 * t + 1];
        const float mm = fmaxf(l0, l1);
        const float p1 = expf(l1 - mm) / (expf(l0 - mm) + expf(l1 - mm));
        if (p1 > best) { best = p1; bidx = t; }
    }
    const float sel0 = s[17 + 2 * bidx], sel1 = s[17 + 2 * bidx + 1];
    float alpha = atanf(sel0 / sel1) + ACENT[bidx];
    const float ray = atanf(locx / depth);
    float roty = alpha + ray;
    if (roty > PI_F) roty -= TWO_PI_F;
    if (roty < -PI_F) roty += TWO_PI_F;
    if (alpha > PI_F) alpha -= TWO_PI_F;
    if (alpha < -PI_F) alpha += TWO_PI_F;

    float* o = out + (size_t)i * 14;
    o[0] = bx1; o[1] = by1; o[2] = bx2; o[3] = by2;
    o[4] = dim0; o[5] = dim1; o[6] = dim2;
    o[7] = depth;
    o[8] = locx; o[9] = locy; o[10] = depth;
    o[11] = roty; o[12] = alpha;
    o[13] = score;
    out[NDET * 14 + i] = valid ? 1.0f : 0.0f;
    out[NDET * 15 + i] = (float)cls;
}

extern "C" void kernel_launch(void* const* d_in, const int* in_sizes, int n_in,
                              void* d_out, int out_size, void* d_ws, size_t ws_size,
                              hipStream_t stream) {
    const float* cls = (const float*)d_in[0];
    const float* regs = (const float*)d_in[1];
    const float* calib = (const float*)d_in[2];
    float* out = (float*)d_out;
    char* ws = (char*)d_ws;

    // ws layout (all regions rewritten each launch before being read)
    int* slabCnt = (int*)ws;                                           // 1152*4 B
    int* fbCnt = (int*)(ws + 8192);                                    // 144*4
    unsigned long long* planeKeys = (unsigned long long*)(ws + 16384); // 57,600 B
    float* dScore = (float*)(ws + 73984);                              // 3200
    int* dInd = (int*)(ws + 77184);                                    // 3200
    int* dCls = (int*)(ws + 80384);                                    // 3200
    unsigned long long* slabs = (unsigned long long*)(ws + 98304);     // 1152*512*8 = 4,718,592
    unsigned long long* fbBuf = (unsigned long long*)(ws + 98304 + 4718592);  // 144*16384*8

    hipLaunchKernelGGL(thresh_scan, dim3(K1CH, NPLANE), dim3(256), 0, stream, cls, slabs, slabCnt);
    hipLaunchKernelGGL(select_topk, dim3(NPLANE), dim3(256), 0, stream, cls, slabs, slabCnt,
                       planeKeys, fbBuf, fbCnt);
    hipLaunchKernelGGL(batch_topk, dim3(NB), dim3(256), 0, stream, planeKeys, dScore, dInd, dCls);
    hipLaunchKernelGGL(finalize, dim3(NDET), dim3(64), 0, stream, regs, calib, dScore, dInd, dCls, out);
}